// Round 18
// baseline (276.984 us; speedup 1.0000x reference)
//
#include <hip/hip_runtime.h>
#include <hip/hip_fp16.h>
#include <math.h>

#define N_NODES 20000
#define N_EDGES 320000
#define NB 128
#define H 32
#define AF 64
#define BF 16
#define SCB 79           // scan blocks: ceil(20000/256)
#define SCP 20224        // padded per-pass partial size (79*256)
#define EMB_BLOCKS 2500
#define PACK_BLOCKS 66   // 33*512/256
#define ZERO_BLOCKS 16

typedef _Float16 f16x2 __attribute__((ext_vector_type(2)));

__device__ __forceinline__ float fast_sigmoid(float x) {
  return 1.0f / (1.0f + __expf(-x));
}
__device__ __forceinline__ float fast_tanh(float x) {
  float e2 = __expf(2.0f * x);
  return 1.0f - 2.0f / (e2 + 1.0f);    // inf-safe
}
// pack two floats as fp16 pair (RNE cast, low = a)
__device__ __forceinline__ unsigned int pk2(float a, float b) {
  union { f16x2 h; unsigned int u; } p;
  p.h[0] = (_Float16)a;
  p.h[1] = (_Float16)b;
  return p.u;
}
// extract half 0/1 of an fp16 pair as float
__device__ __forceinline__ float uph(unsigned int u, int hi) {
  union { unsigned int u; f16x2 h; } x; x.u = u;
  return hi ? (float)x.h[1] : (float)x.h[0];
}
// fp16x2 dot with fp32 accumulate
__device__ __forceinline__ float dot2(unsigned int a, unsigned int b, float c) {
  union { unsigned int u; f16x2 h; } ua, ub;
  ua.u = a; ub.u = b;
#if __has_builtin(__builtin_amdgcn_fdot2)
  return __builtin_amdgcn_fdot2(ua.h, ub.h, c, false);
#else
  return c + (float)ua.h[0] * (float)ub.h[0] + (float)ua.h[1] * (float)ub.h[1];
#endif
}

// ---------------- fused prep: embed_nodes + pack_We2 + hist zero ----------------
__global__ __launch_bounds__(256) void prep(const float* __restrict__ nf,
    const float* __restrict__ W, const float* __restrict__ b, float* __restrict__ h,
    const float* __restrict__ We2, const float* __restrict__ be2,
    unsigned int* __restrict__ Wp, int* __restrict__ hist2buf) {
  int blk = blockIdx.x;
  int tid = threadIdx.x;
  if (blk < EMB_BLOCKS) {
    __shared__ float Ws[AF * H];     // 8 KB
    __shared__ float nfs[8][AF];
    for (int v = tid; v < AF * H; v += 256) Ws[v] = W[v];
    int n0 = blk * 8;
    for (int v = tid; v < 8 * AF; v += 256) {
      int nl = v / AF, k = v % AF;
      nfs[nl][k] = nf[(size_t)(n0 + nl) * AF + k];
    }
    __syncthreads();
    int nl = tid / H, o = tid % H;
    int n = n0 + nl;
    float acc = b[o];
#pragma unroll
    for (int k = 0; k < AF; k++) acc += nfs[nl][k] * Ws[k * H + o];
    h[(size_t)n * H + o] = acc;
  } else if (blk < EMB_BLOCKS + PACK_BLOCKS) {
    int idx = (blk - EMB_BLOCKS) * 256 + tid;
    if (idx < 33 * 512) {
      int j = idx >> 9, r = idx & 511;
      int ip = r >> 5, o = r & 31;
      const float* src = (j < 32) ? (We2 + (size_t)j * (H * H)) : be2;
      Wp[idx] = pk2(src[(2 * ip) * H + o], src[(2 * ip + 1) * H + o]);
    }
  } else {
    int idx = (blk - EMB_BLOCKS - PACK_BLOCKS) * 256 + tid;
    for (int i = idx; i < 2 * N_NODES; i += ZERO_BLOCKS * 256) hist2buf[i] = 0;
  }
}

// ---------------- histograms over src AND dst ----------------
__global__ void hist2(const int* __restrict__ src, const int* __restrict__ dst,
                      int* __restrict__ hsrc, int* __restrict__ hdst) {
  int e = blockIdx.x * 256 + threadIdx.x;
  if (e < N_EDGES) {
    atomicAdd(&hsrc[src[e]], 1);
    atomicAdd(&hdst[dst[e]], 1);
  }
}

// ---------------- multi-block exclusive scan ----------------
__global__ __launch_bounds__(256) void scan_partial(const int* __restrict__ hist_s,
    const int* __restrict__ hist_d, int* __restrict__ part, int* __restrict__ bsum) {
  __shared__ int wsums[4];
  int which = blockIdx.y;
  const int* __restrict__ hh = which ? hist_d : hist_s;
  int i = blockIdx.x * 256 + threadIdx.x;
  int v = (i < N_NODES) ? hh[i] : 0;
  int lane = threadIdx.x & 63, wid = threadIdx.x >> 6;
  int incl = v;
#pragma unroll
  for (int off = 1; off < 64; off <<= 1) {
    int t = __shfl_up(incl, off, 64);
    if (lane >= off) incl += t;
  }
  if (lane == 63) wsums[wid] = incl;
  __syncthreads();
  int woff = 0;
#pragma unroll
  for (int w = 0; w < 4; w++) if (w < wid) woff += wsums[w];
  part[which * SCP + i] = woff + incl - v;
  if (threadIdx.x == 0)
    bsum[which * SCB + blockIdx.x] = wsums[0] + wsums[1] + wsums[2] + wsums[3];
}

// tops scan + graph segment bounds (gid sorted) fused in one tiny block
__global__ __launch_bounds__(256) void scan_tops(int* __restrict__ bsum,
    const int* __restrict__ gid, int* __restrict__ gstart) {
  __shared__ int s[2 * SCB];
  int tid = threadIdx.x;
  if (tid < 2 * SCB) s[tid] = bsum[tid];
  if (tid < NB) {
    int g = tid;
    int lo = 0, hi = N_NODES;
    while (lo < hi) { int mid = (lo + hi) >> 1; if (gid[mid] < g) lo = mid + 1; else hi = mid; }
    gstart[g] = lo;
    if (g == 0) gstart[NB] = N_NODES;
  }
  __syncthreads();
  if (tid < 2) {
    int run = 0;
    for (int b = 0; b < SCB; b++) { int t = s[tid * SCB + b]; s[tid * SCB + b] = run; run += t; }
  }
  __syncthreads();
  if (tid < 2 * SCB) bsum[tid] = s[tid];
}

__global__ __launch_bounds__(256) void scan_final(const int* __restrict__ part,
    const int* __restrict__ bsum, const int* __restrict__ hist_d,
    int* __restrict__ cur_s, int* __restrict__ cur_d,
    int* __restrict__ seg_s, int* __restrict__ seg_d, float* __restrict__ inv_deg) {
  int which = blockIdx.y;
  int i = blockIdx.x * 256 + threadIdx.x;
  if (i >= N_NODES) return;
  int ex = part[which * SCP + i] + bsum[which * SCB + blockIdx.x];
  if (which == 0) {
    cur_s[i] = ex; seg_s[i] = ex;
    if (i == 0) seg_s[N_NODES] = N_EDGES;
  } else {
    cur_d[i] = ex; seg_d[i] = ex;
    inv_deg[i] = 1.0f / fmaxf((float)hist_d[i], 1.0f);
    if (i == 0) seg_d[N_NODES] = N_EDGES;
  }
}

// scatter (fallback path only): materialize src_s/dst_s + pos_s for atomic kernels.
__global__ void scatter2_full(const int* __restrict__ src, const int* __restrict__ dst,
    int* __restrict__ cur_s, int* __restrict__ cur_d,
    int* __restrict__ src_s, int* __restrict__ dst_s,
    int* __restrict__ pos_s, int* __restrict__ dpos) {
  int e = blockIdx.x * 256 + threadIdx.x;
  if (e >= N_EDGES) return;
  int s = src[e], d = dst[e];
  int ps = atomicAdd(&cur_s[s], 1);
  int pd = atomicAdd(&cur_d[d], 1);
  src_s[ps] = s;
  dst_s[ps] = d;
  dpos[ps] = pd;
  pos_s[e] = ps;
}

// ---------------- edge MLP core (fallback edge_r) ----------------
__device__ __forceinline__ uint2 edge_r_core(const float* __restrict__ ef,
    const float* __restrict__ Wb, const float* __restrict__ bb,
    const float* __restrict__ We1, const float* __restrict__ be1,
    float* Wbs, unsigned int* W1p, float* efs, unsigned int* hbp,
    int e0, int tid) {
  for (int v = tid; v < BF * H; v += 256) Wbs[v] = Wb[v];
  for (int v = tid; v < 16 * H; v += 256) {
    int jp = v >> 5, o = v & 31;
    W1p[v] = pk2(We1[(2 * jp) * H + o], We1[(2 * jp + 1) * H + o]);
  }
  if (tid < 128) {        // 32 edges x 16 floats = 128 float4, coalesced
    float4 d = ((const float4*)(ef + (size_t)e0 * BF))[tid];
    ((float4*)(efs + (tid >> 2) * 20))[tid & 3] = d;
  }
  __syncthreads();
  int el = tid >> 3, oq = tid & 7;
  const float4* Wb4 = (const float4*)Wbs;
  const float4* efv = (const float4*)(efs + el * 20);
  float4 hb = ((const float4*)bb)[oq];
#pragma unroll
  for (int kq = 0; kq < 4; kq++) {
    float4 e4 = efv[kq];
    float4 w;
    w = Wb4[(kq * 4 + 0) * 8 + oq];
    hb.x += e4.x * w.x; hb.y += e4.x * w.y; hb.z += e4.x * w.z; hb.w += e4.x * w.w;
    w = Wb4[(kq * 4 + 1) * 8 + oq];
    hb.x += e4.y * w.x; hb.y += e4.y * w.y; hb.z += e4.y * w.z; hb.w += e4.y * w.w;
    w = Wb4[(kq * 4 + 2) * 8 + oq];
    hb.x += e4.z * w.x; hb.y += e4.z * w.y; hb.z += e4.z * w.z; hb.w += e4.z * w.w;
    w = Wb4[(kq * 4 + 3) * 8 + oq];
    hb.x += e4.w * w.x; hb.y += e4.w * w.y; hb.z += e4.w * w.z; hb.w += e4.w * w.w;
  }
  ((uint2*)(hbp + el * 20))[oq] = make_uint2(pk2(hb.x, hb.y), pk2(hb.z, hb.w));
  __syncthreads();
  float4 acc = ((const float4*)be1)[oq];
  const uint4* hb4 = (const uint4*)(hbp + el * 20);
#pragma unroll
  for (int q = 0; q < 4; q++) {
    uint4 hp = hb4[q];                     // jp = 4q..4q+3, 8-lane broadcast
    uint4 w;
    w = ((const uint4*)(W1p + (4 * q + 0) * H))[oq];
    acc.x = dot2(hp.x, w.x, acc.x); acc.y = dot2(hp.x, w.y, acc.y);
    acc.z = dot2(hp.x, w.z, acc.z); acc.w = dot2(hp.x, w.w, acc.w);
    w = ((const uint4*)(W1p + (4 * q + 1) * H))[oq];
    acc.x = dot2(hp.y, w.x, acc.x); acc.y = dot2(hp.y, w.y, acc.y);
    acc.z = dot2(hp.y, w.z, acc.z); acc.w = dot2(hp.y, w.w, acc.w);
    w = ((const uint4*)(W1p + (4 * q + 2) * H))[oq];
    acc.x = dot2(hp.z, w.x, acc.x); acc.y = dot2(hp.z, w.y, acc.y);
    acc.z = dot2(hp.z, w.z, acc.z); acc.w = dot2(hp.z, w.w, acc.w);
    w = ((const uint4*)(W1p + (4 * q + 3) * H))[oq];
    acc.x = dot2(hp.w, w.x, acc.x); acc.y = dot2(hp.w, w.y, acc.y);
    acc.z = dot2(hp.w, w.z, acc.z); acc.w = dot2(hp.w, w.w, acc.w);
  }
  acc.x = fmaxf(acc.x, 0.0f); acc.y = fmaxf(acc.y, 0.0f);
  acc.z = fmaxf(acc.z, 0.0f); acc.w = fmaxf(acc.w, 0.0f);
  uint2 st;
  st.x = pk2(acc.x, acc.y);     // jp = 2*oq
  st.y = pk2(acc.z, acc.w);     // jp = 2*oq+1
  return st;
}

// fast path: edge MLP + inline counting-sort scatter, atomics software-pipelined.
__global__ __launch_bounds__(256) void edge_r_scatter(const float* __restrict__ ef,
    const float* __restrict__ Wb, const float* __restrict__ bb,
    const float* __restrict__ We1, const float* __restrict__ be1,
    const int* __restrict__ src, const int* __restrict__ dst,
    int* __restrict__ cur_s, int* __restrict__ cur_d,
    int* __restrict__ dpos, unsigned int* __restrict__ rh) {
  __shared__ float Wbs[BF * H];           // 2 KB
  __shared__ unsigned int W1p[16 * H];    // 2 KB
  __shared__ float efs[32 * 20];
  __shared__ unsigned int hbp[32 * 20];
  __shared__ int psh[32];
  int tid = threadIdx.x;
  int e0 = blockIdx.x * 32;
  // phase 0: issue atomics, park results in VGPRs (no consumption yet)
  int ps0 = 0, pd0 = 0;
  if (tid < 32) {
    int e = e0 + tid;
    int s = src[e], d = dst[e];
    ps0 = atomicAdd(&cur_s[s], 1);
    pd0 = atomicAdd(&cur_d[d], 1);
  }
  // phase 1: staging
  for (int v = tid; v < BF * H; v += 256) Wbs[v] = Wb[v];
  for (int v = tid; v < 16 * H; v += 256) {
    int jp = v >> 5, o = v & 31;
    W1p[v] = pk2(We1[(2 * jp) * H + o], We1[(2 * jp + 1) * H + o]);
  }
  if (tid < 128) {
    float4 d = ((const float4*)(ef + (size_t)e0 * BF))[tid];
    ((float4*)(efs + (tid >> 2) * 20))[tid & 3] = d;
  }
  __syncthreads();
  int el = tid >> 3, oq = tid & 7;
  const float4* Wb4 = (const float4*)Wbs;
  const float4* efv = (const float4*)(efs + el * 20);
  float4 hb = ((const float4*)bb)[oq];
#pragma unroll
  for (int kq = 0; kq < 4; kq++) {
    float4 e4 = efv[kq];
    float4 w;
    w = Wb4[(kq * 4 + 0) * 8 + oq];
    hb.x += e4.x * w.x; hb.y += e4.x * w.y; hb.z += e4.x * w.z; hb.w += e4.x * w.w;
    w = Wb4[(kq * 4 + 1) * 8 + oq];
    hb.x += e4.y * w.x; hb.y += e4.y * w.y; hb.z += e4.y * w.z; hb.w += e4.y * w.w;
    w = Wb4[(kq * 4 + 2) * 8 + oq];
    hb.x += e4.z * w.x; hb.y += e4.z * w.y; hb.z += e4.z * w.z; hb.w += e4.z * w.w;
    w = Wb4[(kq * 4 + 3) * 8 + oq];
    hb.x += e4.w * w.x; hb.y += e4.w * w.y; hb.z += e4.w * w.z; hb.w += e4.w * w.w;
  }
  ((uint2*)(hbp + el * 20))[oq] = make_uint2(pk2(hb.x, hb.y), pk2(hb.z, hb.w));
  // consume atomic results now — latency covered by phases 1-2
  if (tid < 32) {
    dpos[ps0] = pd0;
    psh[tid] = ps0;
  }
  __syncthreads();
  float4 acc = ((const float4*)be1)[oq];
  const uint4* hb4 = (const uint4*)(hbp + el * 20);
#pragma unroll
  for (int q = 0; q < 4; q++) {
    uint4 hp = hb4[q];
    uint4 w;
    w = ((const uint4*)(W1p + (4 * q + 0) * H))[oq];
    acc.x = dot2(hp.x, w.x, acc.x); acc.y = dot2(hp.x, w.y, acc.y);
    acc.z = dot2(hp.x, w.z, acc.z); acc.w = dot2(hp.x, w.w, acc.w);
    w = ((const uint4*)(W1p + (4 * q + 1) * H))[oq];
    acc.x = dot2(hp.y, w.x, acc.x); acc.y = dot2(hp.y, w.y, acc.y);
    acc.z = dot2(hp.y, w.z, acc.z); acc.w = dot2(hp.y, w.w, acc.w);
    w = ((const uint4*)(W1p + (4 * q + 2) * H))[oq];
    acc.x = dot2(hp.z, w.x, acc.x); acc.y = dot2(hp.z, w.y, acc.y);
    acc.z = dot2(hp.z, w.z, acc.z); acc.w = dot2(hp.z, w.w, acc.w);
    w = ((const uint4*)(W1p + (4 * q + 3) * H))[oq];
    acc.x = dot2(hp.w, w.x, acc.x); acc.y = dot2(hp.w, w.y, acc.y);
    acc.z = dot2(hp.w, w.z, acc.z); acc.w = dot2(hp.w, w.w, acc.w);
  }
  acc.x = fmaxf(acc.x, 0.0f); acc.y = fmaxf(acc.y, 0.0f);
  acc.z = fmaxf(acc.z, 0.0f); acc.w = fmaxf(acc.w, 0.0f);
  int ps = psh[el];
  uint2 st;
  st.x = pk2(acc.x, acc.y);
  st.y = pk2(acc.z, acc.w);
  ((uint2*)(rh + (size_t)ps * 16))[oq] = st;
}

// fallback path: edge MLP gathered through precomputed pos_s
__global__ __launch_bounds__(256) void edge_r(const float* __restrict__ ef,
    const float* __restrict__ Wb, const float* __restrict__ bb,
    const float* __restrict__ We1, const float* __restrict__ be1,
    const int* __restrict__ pos_s, unsigned int* __restrict__ rh) {
  __shared__ float Wbs[BF * H];
  __shared__ unsigned int W1p[16 * H];
  __shared__ float efs[32 * 20];
  __shared__ unsigned int hbp[32 * 20];
  int tid = threadIdx.x;
  int e0 = blockIdx.x * 32;
  uint2 st = edge_r_core(ef, Wb, bb, We1, be1, Wbs, W1p, efs, hbp, e0, tid);
  int el = tid >> 3, oq = tid & 7;
  int ps = pos_s[e0 + el];
  ((uint2*)(rh + (size_t)ps * 16))[oq] = st;
}

// ---------------- msg phase core: T+hbias into LDS, then edge loop ----------------
// Phase B v2: each wave OWNS segments (wid, wid+4) — hoists per block drop 32 -> 8
// (R17 interleaved all 4 waves across all 8 segments: 512 b128 of tw re-reads per
// block, ~25 us/kernel of LDS pipe). rr/dpos loads software-pipelined per chunk.
__device__ __forceinline__ void msg_phase(const unsigned int* __restrict__ Wp,
    const unsigned int* __restrict__ rh, const int* __restrict__ dpos,
    unsigned int* __restrict__ msg_out,
    unsigned int* Ts, const unsigned int* hp, float* hb, const int* sseg, int tid) {
  // Phase A1: T. thread = (jp 0..15, oh 0..15); owns o = {2oh,2oh+1}, j = {2jp,2jp+1}
  {
    int jp = tid >> 4, oh = tid & 15;
    uint2 w0[16], w1[16];
    const unsigned int* W0 = Wp + (size_t)(2 * jp) * 512 + 2 * oh;
    const unsigned int* W1 = Wp + (size_t)(2 * jp + 1) * 512 + 2 * oh;
#pragma unroll
    for (int ip = 0; ip < 16; ip++) {
      w0[ip] = *(const uint2*)(W0 + ip * 32);
      w1[ip] = *(const uint2*)(W1 + ip * 32);
    }
#pragma unroll
    for (int nl = 0; nl < 8; nl++) {
      uint4 h0 = ((const uint4*)(hp + nl * 16))[0];
      uint4 h1 = ((const uint4*)(hp + nl * 16))[1];
      uint4 h2 = ((const uint4*)(hp + nl * 16))[2];
      uint4 h3 = ((const uint4*)(hp + nl * 16))[3];
      unsigned int hr[16] = {h0.x, h0.y, h0.z, h0.w, h1.x, h1.y, h1.z, h1.w,
                             h2.x, h2.y, h2.z, h2.w, h3.x, h3.y, h3.z, h3.w};
      float t00 = 0.f, t01 = 0.f, t10 = 0.f, t11 = 0.f;
#pragma unroll
      for (int ip = 0; ip < 16; ip++) {
        unsigned int hpv = hr[ip];
        t00 = dot2(hpv, w0[ip].x, t00);
        t01 = dot2(hpv, w0[ip].y, t01);
        t10 = dot2(hpv, w1[ip].x, t10);
        t11 = dot2(hpv, w1[ip].y, t11);
      }
      ((uint2*)(Ts + nl * 512 + jp * 32 + 2 * oh))[0] =
          make_uint2(pk2(t00, t10), pk2(t01, t11));
    }
  }
  // Phase A2: hbias. thread = (nl 0..7, o 0..31)
  {
    int nl = tid >> 5, o = tid & 31;
    const unsigned int* Wb32 = Wp + (size_t)32 * 512 + o;
    float acc = 0.f;
#pragma unroll
    for (int ip = 0; ip < 16; ip++)
      acc = dot2(hp[nl * 16 + ip], Wb32[ip * 32], acc);
    hb[nl * H + o] = acc;
  }
  __syncthreads();
  // Phase B: wave wid owns segments wid and wid+4; pipelined chunk loop
  int lane = tid & 63, wid = tid >> 6;
  int el = lane >> 3, t = lane & 7;
#pragma unroll
  for (int si = 0; si < 2; si++) {
    int s = wid + si * 4;
    int a = sseg[s], bnd = sseg[s + 1];
    if (a >= bnd) continue;
    const unsigned int* Trow = Ts + s * 512;
    uint4 tw[16];
#pragma unroll
    for (int jp = 0; jp < 16; jp++) tw[jp] = ((const uint4*)(Trow + jp * 32))[t];
    float4 hbv = ((const float4*)(hb + s * H))[t];
    // prologue: load chunk 0
    int e = a + el;
    bool valid = (e < bnd);
    int pd = 0;
    uint4 r0 = make_uint4(0u,0u,0u,0u), r1 = r0, r2 = r0, r3 = r0;
    if (valid) {
      pd = dpos[e];
      const uint4* rp = (const uint4*)(rh + (size_t)e * 16);
      r0 = rp[0]; r1 = rp[1]; r2 = rp[2]; r3 = rp[3];
    }
    for (int base = a; base < bnd; base += 8) {
      // prefetch chunk base+8 while computing current
      int e2 = base + 8 + el;
      bool v2 = (base + 8 < bnd) && (e2 < bnd);
      int pd2 = 0;
      uint4 n0 = make_uint4(0u,0u,0u,0u), n1 = n0, n2 = n0, n3 = n0;
      if (v2) {
        pd2 = dpos[e2];
        const uint4* rp = (const uint4*)(rh + (size_t)e2 * 16);
        n0 = rp[0]; n1 = rp[1]; n2 = rp[2]; n3 = rp[3];
      }
      unsigned int rr[16] = {r0.x, r0.y, r0.z, r0.w, r1.x, r1.y, r1.z, r1.w,
                             r2.x, r2.y, r2.z, r2.w, r3.x, r3.y, r3.z, r3.w};
      float4 acc = hbv;
#pragma unroll
      for (int jp = 0; jp < 16; jp++) {
        unsigned int rj = rr[jp];
        uint4 w = tw[jp];
        acc.x = dot2(rj, w.x, acc.x);
        acc.y = dot2(rj, w.y, acc.y);
        acc.z = dot2(rj, w.z, acc.z);
        acc.w = dot2(rj, w.w, acc.w);
      }
      if (valid) {
        uint2 st;
        st.x = pk2(acc.x, acc.y);
        st.y = pk2(acc.z, acc.w);
        ((uint2*)(msg_out + (size_t)pd * 16))[t] = st;
      }
      valid = v2; pd = pd2;
      r0 = n0; r1 = n1; r2 = n2; r3 = n3;
    }
  }
}

// ---------------- layer-1 messages: T from h (global) + edge loop ----------------
__global__ __launch_bounds__(256) void edge_msg_T(const float* __restrict__ h,
    const unsigned int* __restrict__ Wp, const unsigned int* __restrict__ rh,
    const int* __restrict__ seg_s, const int* __restrict__ dpos,
    unsigned int* __restrict__ msg_h) {
  __shared__ unsigned int Ts[8 * 512];   // 16 KB
  __shared__ unsigned int hp[8 * 16];
  __shared__ float hb[8 * H];
  __shared__ int sseg[9];
  int tid = threadIdx.x;
  int n0 = blockIdx.x * 8;
  if (tid < 128) {
    int nl = tid >> 4, ip = tid & 15;
    float2 hv = ((const float2*)(h + (size_t)(n0 + nl) * H))[ip];
    hp[nl * 16 + ip] = pk2(hv.x, hv.y);
  }
  if (tid < 9) sseg[tid] = seg_s[n0 + tid];
  __syncthreads();
  msg_phase(Wp, rh, dpos, msg_h, Ts, hp, hb, sseg, tid);
}

// ---------------- FUSED: seg_gru(layer k) + edge messages(layer k+1) ---------------
__global__ __launch_bounds__(256) void gru_msg(const unsigned int* __restrict__ msg_in,
    const int* __restrict__ seg_d, const float* __restrict__ invdeg,
    const float* __restrict__ Wih, const float* __restrict__ Whh,
    const float* __restrict__ bih, const float* __restrict__ bhh,
    float* __restrict__ h,
    const unsigned int* __restrict__ Wp, const unsigned int* __restrict__ rh,
    const int* __restrict__ seg_s, const int* __restrict__ dpos,
    unsigned int* __restrict__ msg_out) {
  __shared__ __align__(16) char smem_u[8 * 512 * 4];   // 16 KB: Wisp+Whsp, then Ts
  unsigned int* Wisp = (unsigned int*)smem_u;          // 96*18 = 1728 uints
  unsigned int* Whsp = Wisp + 96 * 18;                 // 96*18
  unsigned int* Ts   = (unsigned int*)smem_u;          // 8*512 = 4096 uints (overlap)
  __shared__ unsigned int xpk[8 * 18];
  __shared__ unsigned int hpk[8 * 18];
  __shared__ unsigned int hp[8 * 16];    // NEW h packed (survives into msg phase)
  __shared__ float hb[8 * H];
  __shared__ int sseg[9];
  int tid = threadIdx.x;
  int n0 = blockIdx.x * 8;
  for (int v = tid; v < 96 * 16; v += 256) {
    int k = v >> 4, ip = v & 15;
    float2 wi = ((const float2*)Wih)[v];
    float2 wh = ((const float2*)Whh)[v];
    Wisp[k * 18 + ip] = pk2(wi.x, wi.y);
    Whsp[k * 18 + ip] = pk2(wh.x, wh.y);
  }
  if (tid < 9) sseg[tid] = seg_s[n0 + tid];
  int node = tid >> 5, o = tid & 31;
  int n = n0 + node;
  int a = seg_d[n], bseg = seg_d[n + 1];
  int q = o & 3, g = o >> 2;
  float acc[8];
#pragma unroll
  for (int k = 0; k < 8; k++) acc[k] = 0.0f;
  int nrows = bseg - a;
#pragma unroll 2
  for (int p = g; p < nrows; p += 8) {
    uint4 m = ((const uint4*)(msg_in + (size_t)(a + p) * 16))[q];
    acc[0] += uph(m.x, 0); acc[1] += uph(m.x, 1);
    acc[2] += uph(m.y, 0); acc[3] += uph(m.y, 1);
    acc[4] += uph(m.z, 0); acc[5] += uph(m.z, 1);
    acc[6] += uph(m.w, 0); acc[7] += uph(m.w, 1);
  }
#pragma unroll
  for (int k = 0; k < 8; k++) {
    acc[k] += __shfl_xor(acc[k], 4, 32);
    acc[k] += __shfl_xor(acc[k], 8, 32);
    acc[k] += __shfl_xor(acc[k], 16, 32);
  }
  float idg = invdeg[n];
  if (g == 0) {
#pragma unroll
    for (int t = 0; t < 4; t++) {
      float xa = fmaxf(acc[2 * t] * idg, 0.0f);
      float xb = fmaxf(acc[2 * t + 1] * idg, 0.0f);
      xpk[node * 18 + 4 * q + t] = pk2(xa, xb);
    }
  }
  float hval = h[(size_t)n * H + o];
  float hnb = __shfl_xor(hval, 1, 32);
  if (!(o & 1)) hpk[node * 18 + (o >> 1)] = pk2(hval, hnb);
  __syncthreads();
  float gi0 = bih[o], gi1 = bih[H + o], gi2 = bih[2 * H + o];
  float gh0 = bhh[o], gh1 = bhh[H + o], gh2 = bhh[2 * H + o];
  {
    const uint2* xr  = (const uint2*)(xpk + node * 18);
    const uint2* hr  = (const uint2*)(hpk + node * 18);
    const uint2* wi0 = (const uint2*)(Wisp + o * 18);
    const uint2* wi1 = (const uint2*)(Wisp + (H + o) * 18);
    const uint2* wi2 = (const uint2*)(Wisp + (2 * H + o) * 18);
    const uint2* wh0 = (const uint2*)(Whsp + o * 18);
    const uint2* wh1 = (const uint2*)(Whsp + (H + o) * 18);
    const uint2* wh2 = (const uint2*)(Whsp + (2 * H + o) * 18);
#pragma unroll
    for (int t = 0; t < 8; t++) {
      uint2 xv = xr[t], hv = hr[t];
      uint2 a0 = wi0[t], a1 = wi1[t], a2 = wi2[t];
      uint2 b0 = wh0[t], b1 = wh1[t], b2 = wh2[t];
      gi0 = dot2(xv.x, a0.x, gi0); gi0 = dot2(xv.y, a0.y, gi0);
      gi1 = dot2(xv.x, a1.x, gi1); gi1 = dot2(xv.y, a1.y, gi1);
      gi2 = dot2(xv.x, a2.x, gi2); gi2 = dot2(xv.y, a2.y, gi2);
      gh0 = dot2(hv.x, b0.x, gh0); gh0 = dot2(hv.y, b0.y, gh0);
      gh1 = dot2(hv.x, b1.x, gh1); gh1 = dot2(hv.y, b1.y, gh1);
      gh2 = dot2(hv.x, b2.x, gh2); gh2 = dot2(hv.y, b2.y, gh2);
    }
  }
  float rg = fast_sigmoid(gi0 + gh0);
  float zg = fast_sigmoid(gi1 + gh1);
  float ng = fast_tanh(gi2 + rg * gh2);
  float hnew = (1.0f - zg) * ng + zg * hval;
  h[(size_t)n * H + o] = hnew;           // for the final seg_gru
  float hnb2 = __shfl_xor(hnew, 1, 32);
  if (!(o & 1)) hp[node * 16 + (o >> 1)] = pk2(hnew, hnb2);
  __syncthreads();                       // Wisp/Whsp dead; Ts may now overwrite
  msg_phase(Wp, rh, dpos, msg_out, Ts, hp, hb, sseg, tid);
}

// ---------------- final seg_gru (layer 2) ----------------
__global__ __launch_bounds__(256) void seg_gru(const unsigned int* __restrict__ msg_h,
    const int* __restrict__ seg_d, const float* __restrict__ invdeg,
    const float* __restrict__ Wih, const float* __restrict__ Whh,
    const float* __restrict__ bih, const float* __restrict__ bhh,
    float* __restrict__ h) {
  __shared__ unsigned int Wisp[96 * 18];
  __shared__ unsigned int Whsp[96 * 18];
  __shared__ unsigned int xpk[8 * 18];
  __shared__ unsigned int hpk[8 * 18];
  int tid = threadIdx.x;
  for (int v = tid; v < 96 * 16; v += 256) {
    int k = v >> 4, ip = v & 15;
    float2 wi = ((const float2*)Wih)[v];
    float2 wh = ((const float2*)Whh)[v];
    Wisp[k * 18 + ip] = pk2(wi.x, wi.y);
    Whsp[k * 18 + ip] = pk2(wh.x, wh.y);
  }
  int node = tid >> 5, o = tid & 31;
  int n = blockIdx.x * 8 + node;
  int a = seg_d[n], bseg = seg_d[n + 1];
  int q = o & 3, g = o >> 2;
  float acc[8];
#pragma unroll
  for (int k = 0; k < 8; k++) acc[k] = 0.0f;
  int nrows = bseg - a;
#pragma unroll 2
  for (int p = g; p < nrows; p += 8) {
    uint4 m = ((const uint4*)(msg_h + (size_t)(a + p) * 16))[q];
    acc[0] += uph(m.x, 0); acc[1] += uph(m.x, 1);
    acc[2] += uph(m.y, 0); acc[3] += uph(m.y, 1);
    acc[4] += uph(m.z, 0); acc[5] += uph(m.z, 1);
    acc[6] += uph(m.w, 0); acc[7] += uph(m.w, 1);
  }
#pragma unroll
  for (int k = 0; k < 8; k++) {
    acc[k] += __shfl_xor(acc[k], 4, 32);
    acc[k] += __shfl_xor(acc[k], 8, 32);
    acc[k] += __shfl_xor(acc[k], 16, 32);
  }
  float idg = invdeg[n];
  if (g == 0) {
#pragma unroll
    for (int t = 0; t < 4; t++) {
      float xa = fmaxf(acc[2 * t] * idg, 0.0f);
      float xb = fmaxf(acc[2 * t + 1] * idg, 0.0f);
      xpk[node * 18 + 4 * q + t] = pk2(xa, xb);
    }
  }
  float hval = h[(size_t)n * H + o];
  float hnb = __shfl_xor(hval, 1, 32);
  if (!(o & 1)) hpk[node * 18 + (o >> 1)] = pk2(hval, hnb);
  __syncthreads();
  float gi0 = bih[o], gi1 = bih[H + o], gi2 = bih[2 * H + o];
  float gh0 = bhh[o], gh1 = bhh[H + o], gh2 = bhh[2 * H + o];
  const uint2* xr  = (const uint2*)(xpk + node * 18);
  const uint2* hr  = (const uint2*)(hpk + node * 18);
  const uint2* wi0 = (const uint2*)(Wisp + o * 18);
  const uint2* wi1 = (const uint2*)(Wisp + (H + o) * 18);
  const uint2* wi2 = (const uint2*)(Wisp + (2 * H + o) * 18);
  const uint2* wh0 = (const uint2*)(Whsp + o * 18);
  const uint2* wh1 = (const uint2*)(Whsp + (H + o) * 18);
  const uint2* wh2 = (const uint2*)(Whsp + (2 * H + o) * 18);
#pragma unroll
  for (int t = 0; t < 8; t++) {
    uint2 xv = xr[t], hv = hr[t];
    uint2 a0 = wi0[t], a1 = wi1[t], a2 = wi2[t];
    uint2 b0 = wh0[t], b1 = wh1[t], b2 = wh2[t];
    gi0 = dot2(xv.x, a0.x, gi0); gi0 = dot2(xv.y, a0.y, gi0);
    gi1 = dot2(xv.x, a1.x, gi1); gi1 = dot2(xv.y, a1.y, gi1);
    gi2 = dot2(xv.x, a2.x, gi2); gi2 = dot2(xv.y, a2.y, gi2);
    gh0 = dot2(hv.x, b0.x, gh0); gh0 = dot2(hv.y, b0.y, gh0);
    gh1 = dot2(hv.x, b1.x, gh1); gh1 = dot2(hv.y, b1.y, gh1);
    gh2 = dot2(hv.x, b2.x, gh2); gh2 = dot2(hv.y, b2.y, gh2);
  }
  float rg = fast_sigmoid(gi0 + gh0);
  float zg = fast_sigmoid(gi1 + gh1);
  float ng = fast_tanh(gi2 + rg * gh2);
  h[(size_t)n * H + o] = (1.0f - zg) * ng + zg * hval;
}

// ---------------- fallback kernels (workspace too small) ----------------
__global__ __launch_bounds__(256) void compute_T_fused(const float* __restrict__ h,
    const unsigned int* __restrict__ Wp,
    unsigned int* __restrict__ Th, float* __restrict__ hbias) {
  __shared__ unsigned int Wall[9 * 512];
  __shared__ unsigned int hp[32 * 17];
  int tid = threadIdx.x;
  int n0 = blockIdx.x * 32;
  int jb = blockIdx.y;
  int nslice = (jb == 3) ? 9 : 8;
  const uint4* Wsrc = (const uint4*)(Wp + (size_t)jb * 8 * 512);
#pragma unroll
  for (int v = 0; v < 4; v++) ((uint4*)Wall)[tid + v * 256] = Wsrc[tid + v * 256];
  if (jb == 3 && tid < 128)
    ((uint4*)(Wall + 8 * 512))[tid] = ((const uint4*)(Wp + 32 * 512))[tid];
  for (int v = tid; v < 512; v += 256) {
    int nl = v >> 4, ip = v & 15;
    float2 hv = ((const float2*)(h + (size_t)(n0 + nl) * H))[ip];
    hp[nl * 17 + ip] = pk2(hv.x, hv.y);
  }
  __syncthreads();
  int nl = tid >> 3, oq = tid & 7;
  unsigned int hreg[16];
#pragma unroll
  for (int ip = 0; ip < 16; ip++) hreg[ip] = hp[nl * 17 + ip];
  int n = n0 + nl;
  float4 pacc = make_float4(0.f, 0.f, 0.f, 0.f);
  for (int jj = 0; jj < nslice; jj++) {
    const uint4* W4 = (const uint4*)(Wall + jj * 512);
    float4 acc = make_float4(0.f, 0.f, 0.f, 0.f);
#pragma unroll
    for (int ip = 0; ip < 16; ip++) {
      unsigned int hpv = hreg[ip];
      uint4 w = W4[ip * 8 + oq];
      acc.x = dot2(hpv, w.x, acc.x);
      acc.y = dot2(hpv, w.y, acc.y);
      acc.z = dot2(hpv, w.z, acc.z);
      acc.w = dot2(hpv, w.w, acc.w);
    }
    int j = jb * 8 + jj;
    if (j < H) {
      if (jj & 1) {
        uint4 st;
        st.x = pk2(pacc.x, acc.x);
        st.y = pk2(pacc.y, acc.y);
        st.z = pk2(pacc.z, acc.z);
        st.w = pk2(pacc.w, acc.w);
        ((uint4*)(Th + (size_t)n * 512 + (j >> 1) * 32))[oq] = st;
      } else {
        pacc = acc;
      }
    } else {
      ((float4*)(hbias + (size_t)n * H))[oq] = acc;
    }
  }
}

__global__ __launch_bounds__(256) void edge_msg_atomic(const unsigned int* __restrict__ rh,
    const unsigned int* __restrict__ Th, const float* __restrict__ hbias,
    const int* __restrict__ src_s, const int* __restrict__ dst_s,
    float* __restrict__ agg) {
  int tid = threadIdx.x;
  int e0 = blockIdx.x * 32;
  int el = tid >> 3, t = tid & 7;
  int e = e0 + el;
  int s = src_s[e], d = dst_s[e];
  uint2 ru2 = ((const uint2*)(rh + (size_t)e * 16))[t];
  float4 acc = ((const float4*)(hbias + (size_t)s * H))[t];
  const unsigned int* Trow = Th + (size_t)s * 512;
#pragma unroll
  for (int jp = 0; jp < 16; jp++) {
    unsigned int mine = (jp & 1) ? ru2.y : ru2.x;
    unsigned int rj = (unsigned int)__shfl((int)mine, jp >> 1, 8);
    uint4 tw = ((const uint4*)(Trow + jp * 32))[t];
    acc.x = dot2(rj, tw.x, acc.x);
    acc.y = dot2(rj, tw.y, acc.y);
    acc.z = dot2(rj, tw.z, acc.z);
    acc.w = dot2(rj, tw.w, acc.w);
  }
  float* ap = agg + (size_t)d * H + t * 4;
  atomicAdd(ap + 0, acc.x);
  atomicAdd(ap + 1, acc.y);
  atomicAdd(ap + 2, acc.z);
  atomicAdd(ap + 3, acc.w);
}

__global__ __launch_bounds__(256) void gru_update(const float* __restrict__ agg,
    const float* __restrict__ invdeg, const float* __restrict__ Wih,
    const float* __restrict__ Whh, const float* __restrict__ bih,
    const float* __restrict__ bhh, float* __restrict__ h) {
  __shared__ float Wis[3 * H][H + 1];
  __shared__ float Whs[3 * H][H + 1];
  __shared__ float xs[8][H + 1];
  __shared__ float hsm[8][H + 1];
  int tid = threadIdx.x;
  for (int v = tid; v < 3 * H * H; v += 256) {
    int k = v / H, i = v % H;
    Wis[k][i] = Wih[v];
    Whs[k][i] = Whh[v];
  }
  int node = tid >> 5, o = tid & 31;
  int n = blockIdx.x * 8 + node;
  xs[node][o] = fmaxf(agg[(size_t)n * H + o] * invdeg[n], 0.0f);
  float hval = h[(size_t)n * H + o];
  hsm[node][o] = hval;
  __syncthreads();
  float gi0 = bih[o], gi1 = bih[H + o], gi2 = bih[2 * H + o];
  float gh0 = bhh[o], gh1 = bhh[H + o], gh2 = bhh[2 * H + o];
#pragma unroll
  for (int i = 0; i < H; i++) {
    float xi = xs[node][i], hi_ = hsm[node][i];
    gi0 += xi * Wis[o][i];
    gh0 += hi_ * Whs[o][i];
    gi1 += xi * Wis[H + o][i];
    gh1 += hi_ * Whs[H + o][i];
    gi2 += xi * Wis[2 * H + o][i];
    gh2 += hi_ * Whs[2 * H + o][i];
  }
  float rg = fast_sigmoid(gi0 + gh0);
  float zg = fast_sigmoid(gi1 + gh1);
  float ng = fast_tanh(gi2 + rg * gh2);
  h[(size_t)n * H + o] = (1.0f - zg) * ng + zg * hval;
}

// ---------------- graph mean readout: segmented (gid sorted), no atomics -----------
__global__ __launch_bounds__(256) void readout_graph(const float* __restrict__ h,
    const int* __restrict__ gstart, float* __restrict__ out) {
  __shared__ float red[8][H + 1];
  int g = blockIdx.x;
  int a = gstart[g], b = gstart[g + 1];
  int r = threadIdx.x >> 5, o = threadIdx.x & 31;
  float s = 0.0f;
  for (int n = a + r; n < b; n += 8) s += h[(size_t)n * H + o];
  red[r][o] = s;
  __syncthreads();
  if (r == 0) {
    float t = 0.0f;
#pragma unroll
    for (int k = 0; k < 8; k++) t += red[k][o];
    out[g * H + o] = t / fmaxf((float)(b - a), 1.0f);
  }
}

extern "C" void kernel_launch(void* const* d_in, const int* in_sizes, int n_in,
                              void* d_out, int out_size, void* d_ws, size_t ws_size,
                              hipStream_t stream) {
  const float* n_feat = (const float*)d_in[0];
  const float* e_feat = (const float*)d_in[1];
  const int*   src    = (const int*)d_in[2];
  const int*   dst    = (const int*)d_in[3];
  const int*   gid    = (const int*)d_in[4];
  const float* W_atom = (const float*)d_in[5];
  const float* b_atom = (const float*)d_in[6];
  const float* W_bond = (const float*)d_in[7];
  const float* b_bond = (const float*)d_in[8];
  const float* W_e1   = (const float*)d_in[9];
  const float* b_e1   = (const float*)d_in[10];
  const float* W_e2   = (const float*)d_in[11];
  const float* b_e2   = (const float*)d_in[12];
  const float* W_ih   = (const float*)d_in[13];
  const float* W_hh   = (const float*)d_in[14];
  const float* b_ih   = (const float*)d_in[15];
  const float* b_hh   = (const float*)d_in[16];
  float* out = (float*)d_out;

  // workspace carve-up
  char* ws = (char*)d_ws;
  size_t off = 0;
  float*        h      = (float*)(ws + off); off += (size_t)N_NODES * H * 4;     // 2.56 MB
  unsigned int* rh     = (unsigned int*)(ws + off); off += (size_t)N_EDGES * 16 * 4;  // 20.48 MB
  unsigned int* Th     = (unsigned int*)(ws + off); off += (size_t)N_NODES * 512 * 4; // 40.96 MB (fallback; aliased by pos_s)
  float*        hbias  = (float*)(ws + off); off += (size_t)N_NODES * H * 4;     // 2.56 MB (fallback)
  unsigned int* Wp     = (unsigned int*)(ws + off); off += (size_t)33 * 512 * 4; // 67.6 KB
  int*   hist_s = (int*)(ws + off);   off += (size_t)N_NODES * 4;
  int*   hist_d = (int*)(ws + off);   off += (size_t)N_NODES * 4;
  int*   cur_s  = (int*)(ws + off);   off += (size_t)N_NODES * 4;
  int*   cur_d  = (int*)(ws + off);   off += (size_t)N_NODES * 4;
  int*   seg_s  = (int*)(ws + off);   off += (size_t)(N_NODES + 1) * 4;
  int*   seg_d  = (int*)(ws + off);   off += (size_t)(N_NODES + 1) * 4;
  float* invdeg = (float*)(ws + off); off += (size_t)N_NODES * 4;
  int*   part   = (int*)(ws + off);   off += (size_t)2 * SCP * 4;                // 162 KB
  int*   bsum   = (int*)(ws + off);   off += (size_t)2 * SCB * 4;
  int*   src_s  = (int*)(ws + off);   off += (size_t)N_EDGES * 4;                // 1.28 MB (fallback)
  int*   dst_s  = (int*)(ws + off);   off += (size_t)N_EDGES * 4;                // 1.28 MB (fallback)
  int*   dpos   = (int*)(ws + off);   off += (size_t)N_EDGES * 4;                // 1.28 MB
  int*   gstart = (int*)(ws + off);   off += (size_t)(NB + 1) * 4;
  float* agg    = (float*)(ws + off); off += (size_t)N_NODES * H * 4;            // 2.56 MB (fallback)
  unsigned int* msg_h  = (unsigned int*)(ws + off); off += (size_t)N_EDGES * 16 * 4;  // 20.48 MB
  unsigned int* msg_h2 = (unsigned int*)(ws + off); off += (size_t)N_EDGES * 16 * 4;  // 20.48 MB
  int use_msg = (ws_size >= off) ? 1 : 0;
  int* pos_s = (int*)Th;   // alias: fallback only

  // fused prep: embed_nodes + pack_We2 + hist zero (one launch)
  prep<<<EMB_BLOCKS + PACK_BLOCKS + ZERO_BLOCKS, 256, 0, stream>>>(
      n_feat, W_atom, b_atom, h, W_e2, b_e2, Wp, hist_s);

  // dual counting sort: histograms -> multi-block scans
  hist2<<<(N_EDGES + 255) / 256, 256, 0, stream>>>(src, dst, hist_s, hist_d);
  {
    dim3 gs(SCB, 2);
    scan_partial<<<gs, 256, 0, stream>>>(hist_s, hist_d, part, bsum);
    scan_tops<<<1, 256, 0, stream>>>(bsum, gid, gstart);
    scan_final<<<gs, 256, 0, stream>>>(part, bsum, hist_d, cur_s, cur_d,
                                       seg_s, seg_d, invdeg);
  }

  if (use_msg) {
    // edge MLP + inline scatter (atomics pipelined across the MLP)
    edge_r_scatter<<<N_EDGES / 32, 256, 0, stream>>>(e_feat, W_bond, b_bond,
                                                     W_e1, b_e1, src, dst,
                                                     cur_s, cur_d, dpos, rh);
    // layer 1 messages; fused gru(l1)+messages(l2); final gru(l2)
    edge_msg_T<<<N_NODES / 8, 256, 0, stream>>>(h, Wp, rh, seg_s, dpos, msg_h);
    gru_msg<<<N_NODES / 8, 256, 0, stream>>>(msg_h, seg_d, invdeg,
                                             W_ih, W_hh, b_ih, b_hh, h,
                                             Wp, rh, seg_s, dpos, msg_h2);
    seg_gru<<<N_NODES / 8, 256, 0, stream>>>(msg_h2, seg_d, invdeg,
                                             W_ih, W_hh, b_ih, b_hh, h);
  } else {
    scatter2_full<<<(N_EDGES + 255) / 256, 256, 0, stream>>>(src, dst, cur_s, cur_d,
                                                             src_s, dst_s, pos_s, dpos);
    edge_r<<<N_EDGES / 32, 256, 0, stream>>>(e_feat, W_bond, b_bond, W_e1, b_e1,
                                             pos_s, rh);
    for (int layer = 0; layer < 2; layer++) {
      dim3 gT(N_NODES / 32, 4);
      compute_T_fused<<<gT, 256, 0, stream>>>(h, Wp, Th, hbias);
      hipMemsetAsync(agg, 0, (size_t)N_NODES * H * 4, stream);
      edge_msg_atomic<<<N_EDGES / 32, 256, 0, stream>>>(rh, Th, hbias, src_s, dst_s,
                                                        agg);
      gru_update<<<N_NODES / 8, 256, 0, stream>>>(agg, invdeg,
                                                  W_ih, W_hh, b_ih, b_hh, h);
    }
  }

  // graph mean readout (segmented, atomic-free)
  readout_graph<<<NB, 256, 0, stream>>>(h, gstart, out);
}

// Round 19
// 272.882 us; speedup vs baseline: 1.0150x; 1.0150x over previous
//
#include <hip/hip_runtime.h>
#include <hip/hip_fp16.h>
#include <math.h>

#define N_NODES 20000
#define N_EDGES 320000
#define NB 128
#define H 32
#define AF 64
#define BF 16
#define SCB 79           // scan blocks: ceil(20000/256)
#define SCP 20224        // padded per-pass partial size (79*256)
#define EMB_BLOCKS 2500
#define PACK_BLOCKS 66   // 33*512/256
#define ZERO_BLOCKS 16

typedef _Float16 f16x2 __attribute__((ext_vector_type(2)));

__device__ __forceinline__ float fast_sigmoid(float x) {
  return 1.0f / (1.0f + __expf(-x));
}
__device__ __forceinline__ float fast_tanh(float x) {
  float e2 = __expf(2.0f * x);
  return 1.0f - 2.0f / (e2 + 1.0f);    // inf-safe
}
// pack two floats as fp16 pair (RNE cast, low = a)
__device__ __forceinline__ unsigned int pk2(float a, float b) {
  union { f16x2 h; unsigned int u; } p;
  p.h[0] = (_Float16)a;
  p.h[1] = (_Float16)b;
  return p.u;
}
// extract half 0/1 of an fp16 pair as float
__device__ __forceinline__ float uph(unsigned int u, int hi) {
  union { unsigned int u; f16x2 h; } x; x.u = u;
  return hi ? (float)x.h[1] : (float)x.h[0];
}
// fp16x2 dot with fp32 accumulate
__device__ __forceinline__ float dot2(unsigned int a, unsigned int b, float c) {
  union { unsigned int u; f16x2 h; } ua, ub;
  ua.u = a; ub.u = b;
#if __has_builtin(__builtin_amdgcn_fdot2)
  return __builtin_amdgcn_fdot2(ua.h, ub.h, c, false);
#else
  return c + (float)ua.h[0] * (float)ub.h[0] + (float)ua.h[1] * (float)ub.h[1];
#endif
}

// ---------------- fused prep: embed_nodes + pack_We2 + hist zero ----------------
__global__ __launch_bounds__(256) void prep(const float* __restrict__ nf,
    const float* __restrict__ W, const float* __restrict__ b, float* __restrict__ h,
    const float* __restrict__ We2, const float* __restrict__ be2,
    unsigned int* __restrict__ Wp, int* __restrict__ hist2buf) {
  int blk = blockIdx.x;
  int tid = threadIdx.x;
  if (blk < EMB_BLOCKS) {
    __shared__ float Ws[AF * H];     // 8 KB
    __shared__ float nfs[8][AF];
    for (int v = tid; v < AF * H; v += 256) Ws[v] = W[v];
    int n0 = blk * 8;
    for (int v = tid; v < 8 * AF; v += 256) {
      int nl = v / AF, k = v % AF;
      nfs[nl][k] = nf[(size_t)(n0 + nl) * AF + k];
    }
    __syncthreads();
    int nl = tid / H, o = tid % H;
    int n = n0 + nl;
    float acc = b[o];
#pragma unroll
    for (int k = 0; k < AF; k++) acc += nfs[nl][k] * Ws[k * H + o];
    h[(size_t)n * H + o] = acc;
  } else if (blk < EMB_BLOCKS + PACK_BLOCKS) {
    int idx = (blk - EMB_BLOCKS) * 256 + tid;
    if (idx < 33 * 512) {
      int j = idx >> 9, r = idx & 511;
      int ip = r >> 5, o = r & 31;
      const float* src = (j < 32) ? (We2 + (size_t)j * (H * H)) : be2;
      Wp[idx] = pk2(src[(2 * ip) * H + o], src[(2 * ip + 1) * H + o]);
    }
  } else {
    int idx = (blk - EMB_BLOCKS - PACK_BLOCKS) * 256 + tid;
    for (int i = idx; i < 2 * N_NODES; i += ZERO_BLOCKS * 256) hist2buf[i] = 0;
  }
}

// ---------------- histograms over src AND dst ----------------
__global__ void hist2(const int* __restrict__ src, const int* __restrict__ dst,
                      int* __restrict__ hsrc, int* __restrict__ hdst) {
  int e = blockIdx.x * 256 + threadIdx.x;
  if (e < N_EDGES) {
    atomicAdd(&hsrc[src[e]], 1);
    atomicAdd(&hdst[dst[e]], 1);
  }
}

// ---------------- multi-block exclusive scan ----------------
__global__ __launch_bounds__(256) void scan_partial(const int* __restrict__ hist_s,
    const int* __restrict__ hist_d, int* __restrict__ part, int* __restrict__ bsum) {
  __shared__ int wsums[4];
  int which = blockIdx.y;
  const int* __restrict__ hh = which ? hist_d : hist_s;
  int i = blockIdx.x * 256 + threadIdx.x;
  int v = (i < N_NODES) ? hh[i] : 0;
  int lane = threadIdx.x & 63, wid = threadIdx.x >> 6;
  int incl = v;
#pragma unroll
  for (int off = 1; off < 64; off <<= 1) {
    int t = __shfl_up(incl, off, 64);
    if (lane >= off) incl += t;
  }
  if (lane == 63) wsums[wid] = incl;
  __syncthreads();
  int woff = 0;
#pragma unroll
  for (int w = 0; w < 4; w++) if (w < wid) woff += wsums[w];
  part[which * SCP + i] = woff + incl - v;
  if (threadIdx.x == 0)
    bsum[which * SCB + blockIdx.x] = wsums[0] + wsums[1] + wsums[2] + wsums[3];
}

// tops scan + graph segment bounds (gid sorted) fused in one tiny block
__global__ __launch_bounds__(256) void scan_tops(int* __restrict__ bsum,
    const int* __restrict__ gid, int* __restrict__ gstart) {
  __shared__ int s[2 * SCB];
  int tid = threadIdx.x;
  if (tid < 2 * SCB) s[tid] = bsum[tid];
  if (tid < NB) {
    int g = tid;
    int lo = 0, hi = N_NODES;
    while (lo < hi) { int mid = (lo + hi) >> 1; if (gid[mid] < g) lo = mid + 1; else hi = mid; }
    gstart[g] = lo;
    if (g == 0) gstart[NB] = N_NODES;
  }
  __syncthreads();
  if (tid < 2) {
    int run = 0;
    for (int b = 0; b < SCB; b++) { int t = s[tid * SCB + b]; s[tid * SCB + b] = run; run += t; }
  }
  __syncthreads();
  if (tid < 2 * SCB) bsum[tid] = s[tid];
}

__global__ __launch_bounds__(256) void scan_final(const int* __restrict__ part,
    const int* __restrict__ bsum, const int* __restrict__ hist_d,
    int* __restrict__ cur_s, int* __restrict__ cur_d,
    int* __restrict__ seg_s, int* __restrict__ seg_d, float* __restrict__ inv_deg) {
  int which = blockIdx.y;
  int i = blockIdx.x * 256 + threadIdx.x;
  if (i >= N_NODES) return;
  int ex = part[which * SCP + i] + bsum[which * SCB + blockIdx.x];
  if (which == 0) {
    cur_s[i] = ex; seg_s[i] = ex;
    if (i == 0) seg_s[N_NODES] = N_EDGES;
  } else {
    cur_d[i] = ex; seg_d[i] = ex;
    inv_deg[i] = 1.0f / fmaxf((float)hist_d[i], 1.0f);
    if (i == 0) seg_d[N_NODES] = N_EDGES;
  }
}

// scatter (fallback path only): materialize src_s/dst_s + pos_s for atomic kernels.
__global__ void scatter2_full(const int* __restrict__ src, const int* __restrict__ dst,
    int* __restrict__ cur_s, int* __restrict__ cur_d,
    int* __restrict__ src_s, int* __restrict__ dst_s,
    int* __restrict__ pos_s, int* __restrict__ dpos) {
  int e = blockIdx.x * 256 + threadIdx.x;
  if (e >= N_EDGES) return;
  int s = src[e], d = dst[e];
  int ps = atomicAdd(&cur_s[s], 1);
  int pd = atomicAdd(&cur_d[d], 1);
  src_s[ps] = s;
  dst_s[ps] = d;
  dpos[ps] = pd;
  pos_s[e] = ps;
}

// ---------------- edge MLP core (fallback edge_r) ----------------
__device__ __forceinline__ uint2 edge_r_core(const float* __restrict__ ef,
    const float* __restrict__ Wb, const float* __restrict__ bb,
    const float* __restrict__ We1, const float* __restrict__ be1,
    float* Wbs, unsigned int* W1p, float* efs, unsigned int* hbp,
    int e0, int tid) {
  for (int v = tid; v < BF * H; v += 256) Wbs[v] = Wb[v];
  for (int v = tid; v < 16 * H; v += 256) {
    int jp = v >> 5, o = v & 31;
    W1p[v] = pk2(We1[(2 * jp) * H + o], We1[(2 * jp + 1) * H + o]);
  }
  if (tid < 128) {        // 32 edges x 16 floats = 128 float4, coalesced
    float4 d = ((const float4*)(ef + (size_t)e0 * BF))[tid];
    ((float4*)(efs + (tid >> 2) * 20))[tid & 3] = d;
  }
  __syncthreads();
  int el = tid >> 3, oq = tid & 7;
  const float4* Wb4 = (const float4*)Wbs;
  const float4* efv = (const float4*)(efs + el * 20);
  float4 hb = ((const float4*)bb)[oq];
#pragma unroll
  for (int kq = 0; kq < 4; kq++) {
    float4 e4 = efv[kq];
    float4 w;
    w = Wb4[(kq * 4 + 0) * 8 + oq];
    hb.x += e4.x * w.x; hb.y += e4.x * w.y; hb.z += e4.x * w.z; hb.w += e4.x * w.w;
    w = Wb4[(kq * 4 + 1) * 8 + oq];
    hb.x += e4.y * w.x; hb.y += e4.y * w.y; hb.z += e4.y * w.z; hb.w += e4.y * w.w;
    w = Wb4[(kq * 4 + 2) * 8 + oq];
    hb.x += e4.z * w.x; hb.y += e4.z * w.y; hb.z += e4.z * w.z; hb.w += e4.z * w.w;
    w = Wb4[(kq * 4 + 3) * 8 + oq];
    hb.x += e4.w * w.x; hb.y += e4.w * w.y; hb.z += e4.w * w.z; hb.w += e4.w * w.w;
  }
  ((uint2*)(hbp + el * 20))[oq] = make_uint2(pk2(hb.x, hb.y), pk2(hb.z, hb.w));
  __syncthreads();
  float4 acc = ((const float4*)be1)[oq];
  const uint4* hb4 = (const uint4*)(hbp + el * 20);
#pragma unroll
  for (int q = 0; q < 4; q++) {
    uint4 hp = hb4[q];                     // jp = 4q..4q+3, 8-lane broadcast
    uint4 w;
    w = ((const uint4*)(W1p + (4 * q + 0) * H))[oq];
    acc.x = dot2(hp.x, w.x, acc.x); acc.y = dot2(hp.x, w.y, acc.y);
    acc.z = dot2(hp.x, w.z, acc.z); acc.w = dot2(hp.x, w.w, acc.w);
    w = ((const uint4*)(W1p + (4 * q + 1) * H))[oq];
    acc.x = dot2(hp.y, w.x, acc.x); acc.y = dot2(hp.y, w.y, acc.y);
    acc.z = dot2(hp.y, w.z, acc.z); acc.w = dot2(hp.y, w.w, acc.w);
    w = ((const uint4*)(W1p + (4 * q + 2) * H))[oq];
    acc.x = dot2(hp.z, w.x, acc.x); acc.y = dot2(hp.z, w.y, acc.y);
    acc.z = dot2(hp.z, w.z, acc.z); acc.w = dot2(hp.z, w.w, acc.w);
    w = ((const uint4*)(W1p + (4 * q + 3) * H))[oq];
    acc.x = dot2(hp.w, w.x, acc.x); acc.y = dot2(hp.w, w.y, acc.y);
    acc.z = dot2(hp.w, w.z, acc.z); acc.w = dot2(hp.w, w.w, acc.w);
  }
  acc.x = fmaxf(acc.x, 0.0f); acc.y = fmaxf(acc.y, 0.0f);
  acc.z = fmaxf(acc.z, 0.0f); acc.w = fmaxf(acc.w, 0.0f);
  uint2 st;
  st.x = pk2(acc.x, acc.y);     // jp = 2*oq
  st.y = pk2(acc.z, acc.w);     // jp = 2*oq+1
  return st;
}

// fast path: edge MLP + inline counting-sort scatter, atomics software-pipelined.
__global__ __launch_bounds__(256) void edge_r_scatter(const float* __restrict__ ef,
    const float* __restrict__ Wb, const float* __restrict__ bb,
    const float* __restrict__ We1, const float* __restrict__ be1,
    const int* __restrict__ src, const int* __restrict__ dst,
    int* __restrict__ cur_s, int* __restrict__ cur_d,
    int* __restrict__ dpos, unsigned int* __restrict__ rh) {
  __shared__ float Wbs[BF * H];           // 2 KB
  __shared__ unsigned int W1p[16 * H];    // 2 KB
  __shared__ float efs[32 * 20];
  __shared__ unsigned int hbp[32 * 20];
  __shared__ int psh[32];
  int tid = threadIdx.x;
  int e0 = blockIdx.x * 32;
  // phase 0: issue atomics, park results in VGPRs (no consumption yet)
  int ps0 = 0, pd0 = 0;
  if (tid < 32) {
    int e = e0 + tid;
    int s = src[e], d = dst[e];
    ps0 = atomicAdd(&cur_s[s], 1);
    pd0 = atomicAdd(&cur_d[d], 1);
  }
  // phase 1: staging
  for (int v = tid; v < BF * H; v += 256) Wbs[v] = Wb[v];
  for (int v = tid; v < 16 * H; v += 256) {
    int jp = v >> 5, o = v & 31;
    W1p[v] = pk2(We1[(2 * jp) * H + o], We1[(2 * jp + 1) * H + o]);
  }
  if (tid < 128) {
    float4 d = ((const float4*)(ef + (size_t)e0 * BF))[tid];
    ((float4*)(efs + (tid >> 2) * 20))[tid & 3] = d;
  }
  __syncthreads();
  int el = tid >> 3, oq = tid & 7;
  const float4* Wb4 = (const float4*)Wbs;
  const float4* efv = (const float4*)(efs + el * 20);
  float4 hb = ((const float4*)bb)[oq];
#pragma unroll
  for (int kq = 0; kq < 4; kq++) {
    float4 e4 = efv[kq];
    float4 w;
    w = Wb4[(kq * 4 + 0) * 8 + oq];
    hb.x += e4.x * w.x; hb.y += e4.x * w.y; hb.z += e4.x * w.z; hb.w += e4.x * w.w;
    w = Wb4[(kq * 4 + 1) * 8 + oq];
    hb.x += e4.y * w.x; hb.y += e4.y * w.y; hb.z += e4.y * w.z; hb.w += e4.y * w.w;
    w = Wb4[(kq * 4 + 2) * 8 + oq];
    hb.x += e4.z * w.x; hb.y += e4.z * w.y; hb.z += e4.z * w.z; hb.w += e4.z * w.w;
    w = Wb4[(kq * 4 + 3) * 8 + oq];
    hb.x += e4.w * w.x; hb.y += e4.w * w.y; hb.z += e4.w * w.z; hb.w += e4.w * w.w;
  }
  ((uint2*)(hbp + el * 20))[oq] = make_uint2(pk2(hb.x, hb.y), pk2(hb.z, hb.w));
  // consume atomic results now — latency covered by phases 1-2
  if (tid < 32) {
    dpos[ps0] = pd0;
    psh[tid] = ps0;
  }
  __syncthreads();
  float4 acc = ((const float4*)be1)[oq];
  const uint4* hb4 = (const uint4*)(hbp + el * 20);
#pragma unroll
  for (int q = 0; q < 4; q++) {
    uint4 hp = hb4[q];
    uint4 w;
    w = ((const uint4*)(W1p + (4 * q + 0) * H))[oq];
    acc.x = dot2(hp.x, w.x, acc.x); acc.y = dot2(hp.x, w.y, acc.y);
    acc.z = dot2(hp.x, w.z, acc.z); acc.w = dot2(hp.x, w.w, acc.w);
    w = ((const uint4*)(W1p + (4 * q + 1) * H))[oq];
    acc.x = dot2(hp.y, w.x, acc.x); acc.y = dot2(hp.y, w.y, acc.y);
    acc.z = dot2(hp.y, w.z, acc.z); acc.w = dot2(hp.y, w.w, acc.w);
    w = ((const uint4*)(W1p + (4 * q + 2) * H))[oq];
    acc.x = dot2(hp.z, w.x, acc.x); acc.y = dot2(hp.z, w.y, acc.y);
    acc.z = dot2(hp.z, w.z, acc.z); acc.w = dot2(hp.z, w.w, acc.w);
    w = ((const uint4*)(W1p + (4 * q + 3) * H))[oq];
    acc.x = dot2(hp.w, w.x, acc.x); acc.y = dot2(hp.w, w.y, acc.y);
    acc.z = dot2(hp.w, w.z, acc.z); acc.w = dot2(hp.w, w.w, acc.w);
  }
  acc.x = fmaxf(acc.x, 0.0f); acc.y = fmaxf(acc.y, 0.0f);
  acc.z = fmaxf(acc.z, 0.0f); acc.w = fmaxf(acc.w, 0.0f);
  int ps = psh[el];
  uint2 st;
  st.x = pk2(acc.x, acc.y);
  st.y = pk2(acc.z, acc.w);
  ((uint2*)(rh + (size_t)ps * 16))[oq] = st;
}

// fallback path: edge MLP gathered through precomputed pos_s
__global__ __launch_bounds__(256) void edge_r(const float* __restrict__ ef,
    const float* __restrict__ Wb, const float* __restrict__ bb,
    const float* __restrict__ We1, const float* __restrict__ be1,
    const int* __restrict__ pos_s, unsigned int* __restrict__ rh) {
  __shared__ float Wbs[BF * H];
  __shared__ unsigned int W1p[16 * H];
  __shared__ float efs[32 * 20];
  __shared__ unsigned int hbp[32 * 20];
  int tid = threadIdx.x;
  int e0 = blockIdx.x * 32;
  uint2 st = edge_r_core(ef, Wb, bb, We1, be1, Wbs, W1p, efs, hbp, e0, tid);
  int el = tid >> 3, oq = tid & 7;
  int ps = pos_s[e0 + el];
  ((uint2*)(rh + (size_t)ps * 16))[oq] = st;
}

// ---------------- msg phase core: T+hbias into LDS, then edge loop ----------------
// Phase B v3: R17's interleaved waves + rotation (load balance) but NO tw hoist —
// tw read directly from LDS per octet (16 b128/octet exact, the minimum; hoisting
// costs ~32 b128/octet at avg segment 0.5 octets/wave — R13/R17/R18 all overpaid).
__device__ __forceinline__ void msg_phase(const unsigned int* __restrict__ Wp,
    const unsigned int* __restrict__ rh, const int* __restrict__ dpos,
    unsigned int* __restrict__ msg_out,
    unsigned int* Ts, const unsigned int* hp, float* hb, const int* sseg, int tid) {
  // Phase A1: T. thread = (jp 0..15, oh 0..15); owns o = {2oh,2oh+1}, j = {2jp,2jp+1}
  {
    int jp = tid >> 4, oh = tid & 15;
    uint2 w0[16], w1[16];
    const unsigned int* W0 = Wp + (size_t)(2 * jp) * 512 + 2 * oh;
    const unsigned int* W1 = Wp + (size_t)(2 * jp + 1) * 512 + 2 * oh;
#pragma unroll
    for (int ip = 0; ip < 16; ip++) {
      w0[ip] = *(const uint2*)(W0 + ip * 32);
      w1[ip] = *(const uint2*)(W1 + ip * 32);
    }
#pragma unroll
    for (int nl = 0; nl < 8; nl++) {
      uint4 h0 = ((const uint4*)(hp + nl * 16))[0];
      uint4 h1 = ((const uint4*)(hp + nl * 16))[1];
      uint4 h2 = ((const uint4*)(hp + nl * 16))[2];
      uint4 h3 = ((const uint4*)(hp + nl * 16))[3];
      unsigned int hr[16] = {h0.x, h0.y, h0.z, h0.w, h1.x, h1.y, h1.z, h1.w,
                             h2.x, h2.y, h2.z, h2.w, h3.x, h3.y, h3.z, h3.w};
      float t00 = 0.f, t01 = 0.f, t10 = 0.f, t11 = 0.f;
#pragma unroll
      for (int ip = 0; ip < 16; ip++) {
        unsigned int hpv = hr[ip];
        t00 = dot2(hpv, w0[ip].x, t00);
        t01 = dot2(hpv, w0[ip].y, t01);
        t10 = dot2(hpv, w1[ip].x, t10);
        t11 = dot2(hpv, w1[ip].y, t11);
      }
      ((uint2*)(Ts + nl * 512 + jp * 32 + 2 * oh))[0] =
          make_uint2(pk2(t00, t10), pk2(t01, t11));
    }
  }
  // Phase A2: hbias. thread = (nl 0..7, o 0..31)
  {
    int nl = tid >> 5, o = tid & 31;
    const unsigned int* Wb32 = Wp + (size_t)32 * 512 + o;
    float acc = 0.f;
#pragma unroll
    for (int ip = 0; ip < 16; ip++)
      acc = dot2(hp[nl * 16 + ip], Wb32[ip * 32], acc);
    hb[nl * H + o] = acc;
  }
  __syncthreads();
  // Phase B: waves interleaved over segments (rotation balances), direct tw reads
  int lane = tid & 63, wid = tid >> 6;
  int el = lane >> 3, t = lane & 7;
  for (int s = 0; s < 8; s++) {
    int a = sseg[s], bnd = sseg[s + 1];
    int ww = (wid + s) & 3;              // rotate wave->chunk mapping per segment
    if (a + ww * 8 >= bnd) continue;     // per-wave skip
    const unsigned int* Trow = Ts + s * 512;
    float4 hbv = ((const float4*)(hb + s * H))[t];
    for (int base = a + ww * 8; base < bnd; base += 32) {
      int e = base + el;
      bool valid = (e < bnd);
      int pd = 0;
      unsigned int rr[16];
#pragma unroll
      for (int k = 0; k < 16; k++) rr[k] = 0u;
      if (valid) {
        pd = dpos[e];
        const uint4* rp = (const uint4*)(rh + (size_t)e * 16);
        *(uint4*)(&rr[0])  = rp[0];
        *(uint4*)(&rr[4])  = rp[1];
        *(uint4*)(&rr[8])  = rp[2];
        *(uint4*)(&rr[12]) = rp[3];
      }
      float4 acc = hbv;
#pragma unroll
      for (int jp = 0; jp < 16; jp++) {
        unsigned int rj = rr[jp];
        uint4 w = ((const uint4*)(Trow + jp * 32))[t];   // direct LDS read
        acc.x = dot2(rj, w.x, acc.x);
        acc.y = dot2(rj, w.y, acc.y);
        acc.z = dot2(rj, w.z, acc.z);
        acc.w = dot2(rj, w.w, acc.w);
      }
      if (valid) {
        uint2 st;
        st.x = pk2(acc.x, acc.y);
        st.y = pk2(acc.z, acc.w);
        ((uint2*)(msg_out + (size_t)pd * 16))[t] = st;
      }
    }
  }
}

// ---------------- layer-1 messages: T from h (global) + edge loop ----------------
__global__ __launch_bounds__(256) void edge_msg_T(const float* __restrict__ h,
    const unsigned int* __restrict__ Wp, const unsigned int* __restrict__ rh,
    const int* __restrict__ seg_s, const int* __restrict__ dpos,
    unsigned int* __restrict__ msg_h) {
  __shared__ unsigned int Ts[8 * 512];   // 16 KB
  __shared__ unsigned int hp[8 * 16];
  __shared__ float hb[8 * H];
  __shared__ int sseg[9];
  int tid = threadIdx.x;
  int n0 = blockIdx.x * 8;
  if (tid < 128) {
    int nl = tid >> 4, ip = tid & 15;
    float2 hv = ((const float2*)(h + (size_t)(n0 + nl) * H))[ip];
    hp[nl * 16 + ip] = pk2(hv.x, hv.y);
  }
  if (tid < 9) sseg[tid] = seg_s[n0 + tid];
  __syncthreads();
  msg_phase(Wp, rh, dpos, msg_h, Ts, hp, hb, sseg, tid);
}

// ---------------- FUSED: seg_gru(layer k) + edge messages(layer k+1) ---------------
__global__ __launch_bounds__(256) void gru_msg(const unsigned int* __restrict__ msg_in,
    const int* __restrict__ seg_d, const float* __restrict__ invdeg,
    const float* __restrict__ Wih, const float* __restrict__ Whh,
    const float* __restrict__ bih, const float* __restrict__ bhh,
    float* __restrict__ h,
    const unsigned int* __restrict__ Wp, const unsigned int* __restrict__ rh,
    const int* __restrict__ seg_s, const int* __restrict__ dpos,
    unsigned int* __restrict__ msg_out) {
  __shared__ __align__(16) char smem_u[8 * 512 * 4];   // 16 KB: Wisp+Whsp, then Ts
  unsigned int* Wisp = (unsigned int*)smem_u;          // 96*18 = 1728 uints
  unsigned int* Whsp = Wisp + 96 * 18;                 // 96*18
  unsigned int* Ts   = (unsigned int*)smem_u;          // 8*512 = 4096 uints (overlap)
  __shared__ unsigned int xpk[8 * 18];
  __shared__ unsigned int hpk[8 * 18];
  __shared__ unsigned int hp[8 * 16];    // NEW h packed (survives into msg phase)
  __shared__ float hb[8 * H];
  __shared__ int sseg[9];
  int tid = threadIdx.x;
  int n0 = blockIdx.x * 8;
  for (int v = tid; v < 96 * 16; v += 256) {
    int k = v >> 4, ip = v & 15;
    float2 wi = ((const float2*)Wih)[v];
    float2 wh = ((const float2*)Whh)[v];
    Wisp[k * 18 + ip] = pk2(wi.x, wi.y);
    Whsp[k * 18 + ip] = pk2(wh.x, wh.y);
  }
  if (tid < 9) sseg[tid] = seg_s[n0 + tid];
  int node = tid >> 5, o = tid & 31;
  int n = n0 + node;
  int a = seg_d[n], bseg = seg_d[n + 1];
  int q = o & 3, g = o >> 2;
  float acc[8];
#pragma unroll
  for (int k = 0; k < 8; k++) acc[k] = 0.0f;
  int nrows = bseg - a;
#pragma unroll 2
  for (int p = g; p < nrows; p += 8) {
    uint4 m = ((const uint4*)(msg_in + (size_t)(a + p) * 16))[q];
    acc[0] += uph(m.x, 0); acc[1] += uph(m.x, 1);
    acc[2] += uph(m.y, 0); acc[3] += uph(m.y, 1);
    acc[4] += uph(m.z, 0); acc[5] += uph(m.z, 1);
    acc[6] += uph(m.w, 0); acc[7] += uph(m.w, 1);
  }
#pragma unroll
  for (int k = 0; k < 8; k++) {
    acc[k] += __shfl_xor(acc[k], 4, 32);
    acc[k] += __shfl_xor(acc[k], 8, 32);
    acc[k] += __shfl_xor(acc[k], 16, 32);
  }
  float idg = invdeg[n];
  if (g == 0) {
#pragma unroll
    for (int t = 0; t < 4; t++) {
      float xa = fmaxf(acc[2 * t] * idg, 0.0f);
      float xb = fmaxf(acc[2 * t + 1] * idg, 0.0f);
      xpk[node * 18 + 4 * q + t] = pk2(xa, xb);
    }
  }
  float hval = h[(size_t)n * H + o];
  float hnb = __shfl_xor(hval, 1, 32);
  if (!(o & 1)) hpk[node * 18 + (o >> 1)] = pk2(hval, hnb);
  __syncthreads();
  float gi0 = bih[o], gi1 = bih[H + o], gi2 = bih[2 * H + o];
  float gh0 = bhh[o], gh1 = bhh[H + o], gh2 = bhh[2 * H + o];
  {
    const uint2* xr  = (const uint2*)(xpk + node * 18);
    const uint2* hr  = (const uint2*)(hpk + node * 18);
    const uint2* wi0 = (const uint2*)(Wisp + o * 18);
    const uint2* wi1 = (const uint2*)(Wisp + (H + o) * 18);
    const uint2* wi2 = (const uint2*)(Wisp + (2 * H + o) * 18);
    const uint2* wh0 = (const uint2*)(Whsp + o * 18);
    const uint2* wh1 = (const uint2*)(Whsp + (H + o) * 18);
    const uint2* wh2 = (const uint2*)(Whsp + (2 * H + o) * 18);
#pragma unroll
    for (int t = 0; t < 8; t++) {
      uint2 xv = xr[t], hv = hr[t];
      uint2 a0 = wi0[t], a1 = wi1[t], a2 = wi2[t];
      uint2 b0 = wh0[t], b1 = wh1[t], b2 = wh2[t];
      gi0 = dot2(xv.x, a0.x, gi0); gi0 = dot2(xv.y, a0.y, gi0);
      gi1 = dot2(xv.x, a1.x, gi1); gi1 = dot2(xv.y, a1.y, gi1);
      gi2 = dot2(xv.x, a2.x, gi2); gi2 = dot2(xv.y, a2.y, gi2);
      gh0 = dot2(hv.x, b0.x, gh0); gh0 = dot2(hv.y, b0.y, gh0);
      gh1 = dot2(hv.x, b1.x, gh1); gh1 = dot2(hv.y, b1.y, gh1);
      gh2 = dot2(hv.x, b2.x, gh2); gh2 = dot2(hv.y, b2.y, gh2);
    }
  }
  float rg = fast_sigmoid(gi0 + gh0);
  float zg = fast_sigmoid(gi1 + gh1);
  float ng = fast_tanh(gi2 + rg * gh2);
  float hnew = (1.0f - zg) * ng + zg * hval;
  h[(size_t)n * H + o] = hnew;           // for the final seg_gru
  float hnb2 = __shfl_xor(hnew, 1, 32);
  if (!(o & 1)) hp[node * 16 + (o >> 1)] = pk2(hnew, hnb2);
  __syncthreads();                       // Wisp/Whsp dead; Ts may now overwrite
  msg_phase(Wp, rh, dpos, msg_out, Ts, hp, hb, sseg, tid);
}

// ---------------- final seg_gru (layer 2) ----------------
__global__ __launch_bounds__(256) void seg_gru(const unsigned int* __restrict__ msg_h,
    const int* __restrict__ seg_d, const float* __restrict__ invdeg,
    const float* __restrict__ Wih, const float* __restrict__ Whh,
    const float* __restrict__ bih, const float* __restrict__ bhh,
    float* __restrict__ h) {
  __shared__ unsigned int Wisp[96 * 18];
  __shared__ unsigned int Whsp[96 * 18];
  __shared__ unsigned int xpk[8 * 18];
  __shared__ unsigned int hpk[8 * 18];
  int tid = threadIdx.x;
  for (int v = tid; v < 96 * 16; v += 256) {
    int k = v >> 4, ip = v & 15;
    float2 wi = ((const float2*)Wih)[v];
    float2 wh = ((const float2*)Whh)[v];
    Wisp[k * 18 + ip] = pk2(wi.x, wi.y);
    Whsp[k * 18 + ip] = pk2(wh.x, wh.y);
  }
  int node = tid >> 5, o = tid & 31;
  int n = blockIdx.x * 8 + node;
  int a = seg_d[n], bseg = seg_d[n + 1];
  int q = o & 3, g = o >> 2;
  float acc[8];
#pragma unroll
  for (int k = 0; k < 8; k++) acc[k] = 0.0f;
  int nrows = bseg - a;
#pragma unroll 2
  for (int p = g; p < nrows; p += 8) {
    uint4 m = ((const uint4*)(msg_h + (size_t)(a + p) * 16))[q];
    acc[0] += uph(m.x, 0); acc[1] += uph(m.x, 1);
    acc[2] += uph(m.y, 0); acc[3] += uph(m.y, 1);
    acc[4] += uph(m.z, 0); acc[5] += uph(m.z, 1);
    acc[6] += uph(m.w, 0); acc[7] += uph(m.w, 1);
  }
#pragma unroll
  for (int k = 0; k < 8; k++) {
    acc[k] += __shfl_xor(acc[k], 4, 32);
    acc[k] += __shfl_xor(acc[k], 8, 32);
    acc[k] += __shfl_xor(acc[k], 16, 32);
  }
  float idg = invdeg[n];
  if (g == 0) {
#pragma unroll
    for (int t = 0; t < 4; t++) {
      float xa = fmaxf(acc[2 * t] * idg, 0.0f);
      float xb = fmaxf(acc[2 * t + 1] * idg, 0.0f);
      xpk[node * 18 + 4 * q + t] = pk2(xa, xb);
    }
  }
  float hval = h[(size_t)n * H + o];
  float hnb = __shfl_xor(hval, 1, 32);
  if (!(o & 1)) hpk[node * 18 + (o >> 1)] = pk2(hval, hnb);
  __syncthreads();
  float gi0 = bih[o], gi1 = bih[H + o], gi2 = bih[2 * H + o];
  float gh0 = bhh[o], gh1 = bhh[H + o], gh2 = bhh[2 * H + o];
  const uint2* xr  = (const uint2*)(xpk + node * 18);
  const uint2* hr  = (const uint2*)(hpk + node * 18);
  const uint2* wi0 = (const uint2*)(Wisp + o * 18);
  const uint2* wi1 = (const uint2*)(Wisp + (H + o) * 18);
  const uint2* wi2 = (const uint2*)(Wisp + (2 * H + o) * 18);
  const uint2* wh0 = (const uint2*)(Whsp + o * 18);
  const uint2* wh1 = (const uint2*)(Whsp + (H + o) * 18);
  const uint2* wh2 = (const uint2*)(Whsp + (2 * H + o) * 18);
#pragma unroll
  for (int t = 0; t < 8; t++) {
    uint2 xv = xr[t], hv = hr[t];
    uint2 a0 = wi0[t], a1 = wi1[t], a2 = wi2[t];
    uint2 b0 = wh0[t], b1 = wh1[t], b2 = wh2[t];
    gi0 = dot2(xv.x, a0.x, gi0); gi0 = dot2(xv.y, a0.y, gi0);
    gi1 = dot2(xv.x, a1.x, gi1); gi1 = dot2(xv.y, a1.y, gi1);
    gi2 = dot2(xv.x, a2.x, gi2); gi2 = dot2(xv.y, a2.y, gi2);
    gh0 = dot2(hv.x, b0.x, gh0); gh0 = dot2(hv.y, b0.y, gh0);
    gh1 = dot2(hv.x, b1.x, gh1); gh1 = dot2(hv.y, b1.y, gh1);
    gh2 = dot2(hv.x, b2.x, gh2); gh2 = dot2(hv.y, b2.y, gh2);
  }
  float rg = fast_sigmoid(gi0 + gh0);
  float zg = fast_sigmoid(gi1 + gh1);
  float ng = fast_tanh(gi2 + rg * gh2);
  h[(size_t)n * H + o] = (1.0f - zg) * ng + zg * hval;
}

// ---------------- fallback kernels (workspace too small) ----------------
__global__ __launch_bounds__(256) void compute_T_fused(const float* __restrict__ h,
    const unsigned int* __restrict__ Wp,
    unsigned int* __restrict__ Th, float* __restrict__ hbias) {
  __shared__ unsigned int Wall[9 * 512];
  __shared__ unsigned int hp[32 * 17];
  int tid = threadIdx.x;
  int n0 = blockIdx.x * 32;
  int jb = blockIdx.y;
  int nslice = (jb == 3) ? 9 : 8;
  const uint4* Wsrc = (const uint4*)(Wp + (size_t)jb * 8 * 512);
#pragma unroll
  for (int v = 0; v < 4; v++) ((uint4*)Wall)[tid + v * 256] = Wsrc[tid + v * 256];
  if (jb == 3 && tid < 128)
    ((uint4*)(Wall + 8 * 512))[tid] = ((const uint4*)(Wp + 32 * 512))[tid];
  for (int v = tid; v < 512; v += 256) {
    int nl = v >> 4, ip = v & 15;
    float2 hv = ((const float2*)(h + (size_t)(n0 + nl) * H))[ip];
    hp[nl * 17 + ip] = pk2(hv.x, hv.y);
  }
  __syncthreads();
  int nl = tid >> 3, oq = tid & 7;
  unsigned int hreg[16];
#pragma unroll
  for (int ip = 0; ip < 16; ip++) hreg[ip] = hp[nl * 17 + ip];
  int n = n0 + nl;
  float4 pacc = make_float4(0.f, 0.f, 0.f, 0.f);
  for (int jj = 0; jj < nslice; jj++) {
    const uint4* W4 = (const uint4*)(Wall + jj * 512);
    float4 acc = make_float4(0.f, 0.f, 0.f, 0.f);
#pragma unroll
    for (int ip = 0; ip < 16; ip++) {
      unsigned int hpv = hreg[ip];
      uint4 w = W4[ip * 8 + oq];
      acc.x = dot2(hpv, w.x, acc.x);
      acc.y = dot2(hpv, w.y, acc.y);
      acc.z = dot2(hpv, w.z, acc.z);
      acc.w = dot2(hpv, w.w, acc.w);
    }
    int j = jb * 8 + jj;
    if (j < H) {
      if (jj & 1) {
        uint4 st;
        st.x = pk2(pacc.x, acc.x);
        st.y = pk2(pacc.y, acc.y);
        st.z = pk2(pacc.z, acc.z);
        st.w = pk2(pacc.w, acc.w);
        ((uint4*)(Th + (size_t)n * 512 + (j >> 1) * 32))[oq] = st;
      } else {
        pacc = acc;
      }
    } else {
      ((float4*)(hbias + (size_t)n * H))[oq] = acc;
    }
  }
}

__global__ __launch_bounds__(256) void edge_msg_atomic(const unsigned int* __restrict__ rh,
    const unsigned int* __restrict__ Th, const float* __restrict__ hbias,
    const int* __restrict__ src_s, const int* __restrict__ dst_s,
    float* __restrict__ agg) {
  int tid = threadIdx.x;
  int e0 = blockIdx.x * 32;
  int el = tid >> 3, t = tid & 7;
  int e = e0 + el;
  int s = src_s[e], d = dst_s[e];
  uint2 ru2 = ((const uint2*)(rh + (size_t)e * 16))[t];
  float4 acc = ((const float4*)(hbias + (size_t)s * H))[t];
  const unsigned int* Trow = Th + (size_t)s * 512;
#pragma unroll
  for (int jp = 0; jp < 16; jp++) {
    unsigned int mine = (jp & 1) ? ru2.y : ru2.x;
    unsigned int rj = (unsigned int)__shfl((int)mine, jp >> 1, 8);
    uint4 tw = ((const uint4*)(Trow + jp * 32))[t];
    acc.x = dot2(rj, tw.x, acc.x);
    acc.y = dot2(rj, tw.y, acc.y);
    acc.z = dot2(rj, tw.z, acc.z);
    acc.w = dot2(rj, tw.w, acc.w);
  }
  float* ap = agg + (size_t)d * H + t * 4;
  atomicAdd(ap + 0, acc.x);
  atomicAdd(ap + 1, acc.y);
  atomicAdd(ap + 2, acc.z);
  atomicAdd(ap + 3, acc.w);
}

__global__ __launch_bounds__(256) void gru_update(const float* __restrict__ agg,
    const float* __restrict__ invdeg, const float* __restrict__ Wih,
    const float* __restrict__ Whh, const float* __restrict__ bih,
    const float* __restrict__ bhh, float* __restrict__ h) {
  __shared__ float Wis[3 * H][H + 1];
  __shared__ float Whs[3 * H][H + 1];
  __shared__ float xs[8][H + 1];
  __shared__ float hsm[8][H + 1];
  int tid = threadIdx.x;
  for (int v = tid; v < 3 * H * H; v += 256) {
    int k = v / H, i = v % H;
    Wis[k][i] = Wih[v];
    Whs[k][i] = Whh[v];
  }
  int node = tid >> 5, o = tid & 31;
  int n = blockIdx.x * 8 + node;
  xs[node][o] = fmaxf(agg[(size_t)n * H + o] * invdeg[n], 0.0f);
  float hval = h[(size_t)n * H + o];
  hsm[node][o] = hval;
  __syncthreads();
  float gi0 = bih[o], gi1 = bih[H + o], gi2 = bih[2 * H + o];
  float gh0 = bhh[o], gh1 = bhh[H + o], gh2 = bhh[2 * H + o];
#pragma unroll
  for (int i = 0; i < H; i++) {
    float xi = xs[node][i], hi_ = hsm[node][i];
    gi0 += xi * Wis[o][i];
    gh0 += hi_ * Whs[o][i];
    gi1 += xi * Wis[H + o][i];
    gh1 += hi_ * Whs[H + o][i];
    gi2 += xi * Wis[2 * H + o][i];
    gh2 += hi_ * Whs[2 * H + o][i];
  }
  float rg = fast_sigmoid(gi0 + gh0);
  float zg = fast_sigmoid(gi1 + gh1);
  float ng = fast_tanh(gi2 + rg * gh2);
  h[(size_t)n * H + o] = (1.0f - zg) * ng + zg * hval;
}

// ---------------- graph mean readout: segmented (gid sorted), no atomics -----------
__global__ __launch_bounds__(256) void readout_graph(const float* __restrict__ h,
    const int* __restrict__ gstart, float* __restrict__ out) {
  __shared__ float red[8][H + 1];
  int g = blockIdx.x;
  int a = gstart[g], b = gstart[g + 1];
  int r = threadIdx.x >> 5, o = threadIdx.x & 31;
  float s = 0.0f;
  for (int n = a + r; n < b; n += 8) s += h[(size_t)n * H + o];
  red[r][o] = s;
  __syncthreads();
  if (r == 0) {
    float t = 0.0f;
#pragma unroll
    for (int k = 0; k < 8; k++) t += red[k][o];
    out[g * H + o] = t / fmaxf((float)(b - a), 1.0f);
  }
}

extern "C" void kernel_launch(void* const* d_in, const int* in_sizes, int n_in,
                              void* d_out, int out_size, void* d_ws, size_t ws_size,
                              hipStream_t stream) {
  const float* n_feat = (const float*)d_in[0];
  const float* e_feat = (const float*)d_in[1];
  const int*   src    = (const int*)d_in[2];
  const int*   dst    = (const int*)d_in[3];
  const int*   gid    = (const int*)d_in[4];
  const float* W_atom = (const float*)d_in[5];
  const float* b_atom = (const float*)d_in[6];
  const float* W_bond = (const float*)d_in[7];
  const float* b_bond = (const float*)d_in[8];
  const float* W_e1   = (const float*)d_in[9];
  const float* b_e1   = (const float*)d_in[10];
  const float* W_e2   = (const float*)d_in[11];
  const float* b_e2   = (const float*)d_in[12];
  const float* W_ih   = (const float*)d_in[13];
  const float* W_hh   = (const float*)d_in[14];
  const float* b_ih   = (const float*)d_in[15];
  const float* b_hh   = (const float*)d_in[16];
  float* out = (float*)d_out;

  // workspace carve-up
  char* ws = (char*)d_ws;
  size_t off = 0;
  float*        h      = (float*)(ws + off); off += (size_t)N_NODES * H * 4;     // 2.56 MB
  unsigned int* rh     = (unsigned int*)(ws + off); off += (size_t)N_EDGES * 16 * 4;  // 20.48 MB
  unsigned int* Th     = (unsigned int*)(ws + off); off += (size_t)N_NODES * 512 * 4; // 40.96 MB (fallback; aliased by pos_s)
  float*        hbias  = (float*)(ws + off); off += (size_t)N_NODES * H * 4;     // 2.56 MB (fallback)
  unsigned int* Wp     = (unsigned int*)(ws + off); off += (size_t)33 * 512 * 4; // 67.6 KB
  int*   hist_s = (int*)(ws + off);   off += (size_t)N_NODES * 4;
  int*   hist_d = (int*)(ws + off);   off += (size_t)N_NODES * 4;
  int*   cur_s  = (int*)(ws + off);   off += (size_t)N_NODES * 4;
  int*   cur_d  = (int*)(ws + off);   off += (size_t)N_NODES * 4;
  int*   seg_s  = (int*)(ws + off);   off += (size_t)(N_NODES + 1) * 4;
  int*   seg_d  = (int*)(ws + off);   off += (size_t)(N_NODES + 1) * 4;
  float* invdeg = (float*)(ws + off); off += (size_t)N_NODES * 4;
  int*   part   = (int*)(ws + off);   off += (size_t)2 * SCP * 4;                // 162 KB
  int*   bsum   = (int*)(ws + off);   off += (size_t)2 * SCB * 4;
  int*   src_s  = (int*)(ws + off);   off += (size_t)N_EDGES * 4;                // 1.28 MB (fallback)
  int*   dst_s  = (int*)(ws + off);   off += (size_t)N_EDGES * 4;                // 1.28 MB (fallback)
  int*   dpos   = (int*)(ws + off);   off += (size_t)N_EDGES * 4;                // 1.28 MB
  int*   gstart = (int*)(ws + off);   off += (size_t)(NB + 1) * 4;
  float* agg    = (float*)(ws + off); off += (size_t)N_NODES * H * 4;            // 2.56 MB (fallback)
  unsigned int* msg_h  = (unsigned int*)(ws + off); off += (size_t)N_EDGES * 16 * 4;  // 20.48 MB
  unsigned int* msg_h2 = (unsigned int*)(ws + off); off += (size_t)N_EDGES * 16 * 4;  // 20.48 MB
  int use_msg = (ws_size >= off) ? 1 : 0;
  int* pos_s = (int*)Th;   // alias: fallback only

  // fused prep: embed_nodes + pack_We2 + hist zero (one launch)
  prep<<<EMB_BLOCKS + PACK_BLOCKS + ZERO_BLOCKS, 256, 0, stream>>>(
      n_feat, W_atom, b_atom, h, W_e2, b_e2, Wp, hist_s);

  // dual counting sort: histograms -> multi-block scans
  hist2<<<(N_EDGES + 255) / 256, 256, 0, stream>>>(src, dst, hist_s, hist_d);
  {
    dim3 gs(SCB, 2);
    scan_partial<<<gs, 256, 0, stream>>>(hist_s, hist_d, part, bsum);
    scan_tops<<<1, 256, 0, stream>>>(bsum, gid, gstart);
    scan_final<<<gs, 256, 0, stream>>>(part, bsum, hist_d, cur_s, cur_d,
                                       seg_s, seg_d, invdeg);
  }

  if (use_msg) {
    // edge MLP + inline scatter (atomics pipelined across the MLP)
    edge_r_scatter<<<N_EDGES / 32, 256, 0, stream>>>(e_feat, W_bond, b_bond,
                                                     W_e1, b_e1, src, dst,
                                                     cur_s, cur_d, dpos, rh);
    // layer 1 messages; fused gru(l1)+messages(l2); final gru(l2)
    edge_msg_T<<<N_NODES / 8, 256, 0, stream>>>(h, Wp, rh, seg_s, dpos, msg_h);
    gru_msg<<<N_NODES / 8, 256, 0, stream>>>(msg_h, seg_d, invdeg,
                                             W_ih, W_hh, b_ih, b_hh, h,
                                             Wp, rh, seg_s, dpos, msg_h2);
    seg_gru<<<N_NODES / 8, 256, 0, stream>>>(msg_h2, seg_d, invdeg,
                                             W_ih, W_hh, b_ih, b_hh, h);
  } else {
    scatter2_full<<<(N_EDGES + 255) / 256, 256, 0, stream>>>(src, dst, cur_s, cur_d,
                                                             src_s, dst_s, pos_s, dpos);
    edge_r<<<N_EDGES / 32, 256, 0, stream>>>(e_feat, W_bond, b_bond, W_e1, b_e1,
                                             pos_s, rh);
    for (int layer = 0; layer < 2; layer++) {
      dim3 gT(N_NODES / 32, 4);
      compute_T_fused<<<gT, 256, 0, stream>>>(h, Wp, Th, hbias);
      hipMemsetAsync(agg, 0, (size_t)N_NODES * H * 4, stream);
      edge_msg_atomic<<<N_EDGES / 32, 256, 0, stream>>>(rh, Th, hbias, src_s, dst_s,
                                                        agg);
      gru_update<<<N_NODES / 8, 256, 0, stream>>>(agg, invdeg,
                                                  W_ih, W_hh, b_ih, b_hh, h);
    }
  }

  // graph mean readout (segmented, atomic-free)
  readout_graph<<<NB, 256, 0, stream>>>(h, gstart, out);
}